// Round 2
// 266.666 us; speedup vs baseline: 1.0959x; 1.0959x over previous
//
#include <hip/hip_runtime.h>
#include <cstddef>
#include <cstdint>

// Problem constants (match reference)
#define BB 16
#define NN 33600
#define CC 80
#define MAXN 100
#define NBINS 4096
#define MAXC 1024
#define SCORE_THR_F 0.05f
#define IOU_THR_F 0.65f

#define NCHUNK 525            // NN / 64
#define K1_CPB 4              // chunks per block
#define K1_GX ((NCHUNK + K1_CPB - 1) / K1_CPB)  // 132
#define K2T 1024              // k2 threads (16 waves)
#define BPT (NBINS / K2T)     // 4 bins per thread in the scan

typedef float f4 __attribute__((ext_vector_type(4)));

// K1: 4 threads per row, 4 row-chunks per block. Computes
// masked = sigmoid(max_c cls)*sigmoid(obj) (-inf if < thr) AND label = argmax_c cls
// (sigmoid is monotone so argmax over raw logits == reference's argmax over sigmoid).
// VALU slack is huge (BW-bound at ~27 us floor), so argmax rides free.
__global__ __launch_bounds__(256) void k1_score(const float* __restrict__ cls,
                                                const float* __restrict__ obj,
                                                float* __restrict__ masked,
                                                unsigned char* __restrict__ labels) {
  const int b = blockIdx.y;
  const int q = threadIdx.x & 3;
  const int r = threadIdx.x >> 2;
  const int c_end = min(blockIdx.x * K1_CPB + K1_CPB, NCHUNK);
  for (int c = blockIdx.x * K1_CPB; c < c_end; c++) {
    const int n = c * 64 + r;
    const f4* row = (const f4*)(cls + ((size_t)b * NN + n) * CC);
    float m = -INFINITY;
    int lab = 0;
#pragma unroll
    for (int j = 0; j < 5; j++) {
      f4 v = __builtin_nontemporal_load(row + q + 4 * j);  // cls is stream-once now
      const int c0 = (q + 4 * j) * 4;
      if (v.x > m) { m = v.x; lab = c0; }      // strict >: first occurrence on ties
      if (v.y > m) { m = v.y; lab = c0 + 1; }
      if (v.z > m) { m = v.z; lab = c0 + 2; }
      if (v.w > m) { m = v.w; lab = c0 + 3; }
    }
#pragma unroll
    for (int d = 1; d < 4; d <<= 1) {
      float m2 = __shfl_xor(m, d, 4);
      int l2 = __shfl_xor(lab, d, 4);
      if (m2 > m || (m2 == m && l2 < lab)) { m = m2; lab = l2; }  // smaller idx on tie
    }
    if (q == 0) {
      const size_t bn = (size_t)b * NN + n;
      float o = obj[bn];
      float s = (1.0f / (1.0f + expf(-m))) * (1.0f / (1.0f + expf(-o)));
      masked[bn] = (s >= SCORE_THR_F) ? s : -INFINITY;
      labels[bn] = (unsigned char)lab;
    }
  }
}

__device__ __forceinline__ int score_bin(float s) {
  return min(NBINS - 1, (int)(s * (float)NBINS));
}

// K2: one block (1024 threads) per batch. Histogram -> wave-shfl suffix scan ->
// compact -> rank-select top-100 -> decode (labels precomputed by k1) ->
// pairwise suppression bitmask -> wave-0 register greedy scan -> write.
__global__ __launch_bounds__(K2T) void k2_all(const float* __restrict__ bbox,
                                              const float* __restrict__ priors,
                                              const float* __restrict__ masked,
                                              const unsigned char* __restrict__ labels,
                                              float* __restrict__ out) {
  const int b = blockIdx.x;
  const int tid = threadIdx.x;
  const int lane = tid & 63;
  const int wv = tid >> 6;  // wave index, 0..15

  __shared__ int hist[NBINS];
  __shared__ int wtot[K2T / 64];
  __shared__ int s_t, s_cnt;
  __shared__ float cs[MAXC];
  __shared__ int ci[MAXC];
  __shared__ int sel[MAXN];               // original anchor index, -1 if empty
  __shared__ float sb[MAXN][4];           // x1,y1,x2,y2
  __shared__ float ssc[MAXN];
  __shared__ int slab[MAXN];
  __shared__ unsigned int sup[MAXN][4];   // suppression bitmask (j bits), j>i only
  __shared__ unsigned long long keep_lo, keep_hi;

  const f4* msc4 = (const f4*)(masked + (size_t)b * NN);

  // Merged init phase (one barrier): hist, sup, sel, scalars
  for (int i = tid; i < NBINS; i += K2T) hist[i] = 0;
  for (int i = tid; i < MAXN * 4; i += K2T) ((unsigned int*)sup)[i] = 0;
  if (tid < MAXN) sel[tid] = -1;
  if (tid == 0) { s_t = 0; s_cnt = 0; }
  __syncthreads();

  // Pass 1: LDS histogram of valid scores (float4 loads; NN/4 = 8400)
  for (int i = tid; i < NN / 4; i += K2T) {
    f4 v = msc4[i];
    if (v.x >= SCORE_THR_F) atomicAdd(&hist[score_bin(v.x)], 1);
    if (v.y >= SCORE_THR_F) atomicAdd(&hist[score_bin(v.y)], 1);
    if (v.z >= SCORE_THR_F) atomicAdd(&hist[score_bin(v.z)], 1);
    if (v.w >= SCORE_THR_F) atomicAdd(&hist[score_bin(v.w)], 1);
  }
  __syncthreads();

  // Suffix scan via wave shuffles: thread t owns bins [t*BPT, t*BPT+BPT).
  // S = suffix count starting at this thread's first bin.
  int gsum = 0;
#pragma unroll
  for (int j = 0; j < BPT; j++) gsum += hist[tid * BPT + j];
  int sfx = gsum;
#pragma unroll
  for (int off = 1; off < 64; off <<= 1) {
    int t2 = __shfl_down(sfx, off);
    if (lane + off < 64) sfx += t2;
  }
  if (lane == 0) wtot[wv] = sfx;
  __syncthreads();
  int offw = 0;
#pragma unroll
  for (int w = 0; w < K2T / 64; w++) offw += (w > wv) ? wtot[w] : 0;
  const int S = sfx + offw;
  // Unique boundary owner: 100 in (S - gsum, S] and gsum > 0
  if (S >= MAXN && S - gsum < MAXN) {
    int running = S - gsum;
    for (int bin = tid * BPT + BPT - 1; bin >= tid * BPT; bin--) {
      running += hist[bin];
      if (running >= MAXN) { s_t = bin; break; }
    }
  }
  __syncthreads();
  const int t = s_t;

  // Pass 2: compact candidates with bin >= t into LDS (masked is L2-hot now)
  for (int i = tid; i < NN / 4; i += K2T) {
    f4 v = msc4[i];
    int base = i * 4;
    if (v.x >= SCORE_THR_F && score_bin(v.x) >= t) {
      int p = atomicAdd(&s_cnt, 1); if (p < MAXC) { cs[p] = v.x; ci[p] = base; }
    }
    if (v.y >= SCORE_THR_F && score_bin(v.y) >= t) {
      int p = atomicAdd(&s_cnt, 1); if (p < MAXC) { cs[p] = v.y; ci[p] = base + 1; }
    }
    if (v.z >= SCORE_THR_F && score_bin(v.z) >= t) {
      int p = atomicAdd(&s_cnt, 1); if (p < MAXC) { cs[p] = v.z; ci[p] = base + 2; }
    }
    if (v.w >= SCORE_THR_F && score_bin(v.w) >= t) {
      int p = atomicAdd(&s_cnt, 1); if (p < MAXC) { cs[p] = v.w; ci[p] = base + 3; }
    }
  }
  __syncthreads();
  const int C = min(s_cnt, MAXC);

  // Rank by counting: rank = #{j : (s_j,i_j) before (s_i,i_i)}; ranks unique
  // (descending score, ascending index on ties — stable argsort semantics).
  for (int i = tid; i < C; i += K2T) {
    float si = cs[i]; int ii = ci[i];
    int r = 0;
    for (int j = 0; j < C; j++) {
      float sj = cs[j]; int ij = ci[j];
      r += (sj > si) || (sj == si && ij < ii);
    }
    if (r < MAXN) { sel[r] = ii; ssc[r] = si; }
  }
  __syncthreads();

  // Decode for the <=100 winners; label comes precomputed from k1
  if (tid < MAXN) {
    int idx = sel[tid];
    if (idx >= 0) {
      f4 p = ((const f4*)priors)[idx];                 // [x*s, y*s, s, s]
      f4 d = ((const f4*)bbox)[(size_t)b * NN + idx];  // [dx, dy, dw, dh]
      float cx = d.x * p.z + p.x;
      float cy = d.y * p.w + p.y;
      float hw = expf(d.z) * p.z * 0.5f;
      float hh = expf(d.w) * p.w * 0.5f;
      sb[tid][0] = cx - hw; sb[tid][1] = cy - hh;
      sb[tid][2] = cx + hw; sb[tid][3] = cy + hh;
      slab[tid] = labels[(size_t)b * NN + idx];
    } else {
      sb[tid][0] = 0.f; sb[tid][1] = 0.f; sb[tid][2] = 0.f; sb[tid][3] = 0.f;
      ssc[tid] = 0.f; slab[tid] = -1;
    }
  }
  __syncthreads();

  // Pairwise IOUs -> suppression bitmask (only j > i, same label, iou >= thr)
  for (int p = tid; p < MAXN * MAXN; p += K2T) {
    int i = p / MAXN, j = p % MAXN;
    if (j > i && sel[i] >= 0 && sel[j] >= 0 && slab[i] == slab[j]) {
      float xx1 = fmaxf(sb[i][0], sb[j][0]);
      float yy1 = fmaxf(sb[i][1], sb[j][1]);
      float xx2 = fminf(sb[i][2], sb[j][2]);
      float yy2 = fminf(sb[i][3], sb[j][3]);
      float inter = fmaxf(xx2 - xx1, 0.f) * fmaxf(yy2 - yy1, 0.f);
      float ai = (sb[i][2] - sb[i][0]) * (sb[i][3] - sb[i][1]);
      float aj = (sb[j][2] - sb[j][0]) * (sb[j][3] - sb[j][1]);
      float iou = inter / (ai + aj - inter + 1e-8f);
      if (iou >= IOU_THR_F) atomicOr(&sup[i][j >> 5], 1u << (j & 31));
    }
  }
  __syncthreads();

  // Greedy scan in wave 0: suppression rows live in lane registers, broadcast
  // via shfl (~5 cyc) instead of serial LDS round-trips (~120 cyc each).
  if (tid < 64) {
    unsigned a0 = sup[lane][0], a1 = sup[lane][1], a2 = sup[lane][2], a3 = sup[lane][3];
    unsigned b0 = 0, b1 = 0, b2 = 0, b3 = 0;
    if (lane + 64 < MAXN) {
      b0 = sup[lane + 64][0]; b1 = sup[lane + 64][1];
      b2 = sup[lane + 64][2]; b3 = sup[lane + 64][3];
    }
    unsigned long long lo = __ballot(sel[lane] >= 0);                          // rows 0..63
    unsigned long long hi = __ballot(lane + 64 < MAXN && sel[lane + 64] >= 0); // rows 64..99
    for (int i = 0; i < MAXN; i++) {
      bool kb = (i < 64) ? ((lo >> i) & 1ull) : ((hi >> (i - 64)) & 1ull);
      if (kb) {  // uniform across the wave: lo/hi identical in all lanes
        unsigned s0, s1, s2, s3;
        if (i < 64) {
          s0 = (unsigned)__shfl((int)a0, i); s1 = (unsigned)__shfl((int)a1, i);
          s2 = (unsigned)__shfl((int)a2, i); s3 = (unsigned)__shfl((int)a3, i);
        } else {
          s0 = (unsigned)__shfl((int)b0, i - 64); s1 = (unsigned)__shfl((int)b1, i - 64);
          s2 = (unsigned)__shfl((int)b2, i - 64); s3 = (unsigned)__shfl((int)b3, i - 64);
        }
        lo &= ~(((unsigned long long)s1 << 32) | s0);
        hi &= ~(((unsigned long long)s3 << 32) | s2);
      }
    }
    if (lane == 0) { keep_lo = lo; keep_hi = hi; }
  }
  __syncthreads();

  // Write output: dets [B,100,6] then keep [B,100] as 0.0/1.0
  if (tid < MAXN) {
    int k = tid;
    unsigned long long kw = (k < 64) ? keep_lo : keep_hi;
    int kbit = (k < 64) ? k : k - 64;
    bool kp = (kw >> kbit) & 1ull;
    float* row = out + ((size_t)b * MAXN + k) * 6;
    if (kp) {
      row[0] = sb[k][0]; row[1] = sb[k][1]; row[2] = sb[k][2]; row[3] = sb[k][3];
      row[4] = ssc[k];   row[5] = (float)slab[k];
    } else {
      row[0] = 0.f; row[1] = 0.f; row[2] = 0.f; row[3] = 0.f;
      row[4] = 0.f; row[5] = -1.f;
    }
    out[(size_t)BB * MAXN * 6 + (size_t)b * MAXN + k] = kp ? 1.0f : 0.0f;
  }
}

extern "C" void kernel_launch(void* const* d_in, const int* in_sizes, int n_in,
                              void* d_out, int out_size, void* d_ws, size_t ws_size,
                              hipStream_t stream) {
  const float* cls    = (const float*)d_in[0];  // [B,N,C]
  const float* bbox   = (const float*)d_in[1];  // [B,N,4]
  const float* obj    = (const float*)d_in[2];  // [B,N]
  const float* priors = (const float*)d_in[3];  // [N,4]
  float* out = (float*)d_out;                   // [B,100,6] ++ [B,100]
  float* masked = (float*)d_ws;                 // [B,N] masked scores (2.15 MB)
  unsigned char* labels = (unsigned char*)(masked + (size_t)BB * NN);  // [B,N] u8

  k1_score<<<dim3(K1_GX, BB), 256, 0, stream>>>(cls, obj, masked, labels);
  k2_all<<<BB, K2T, 0, stream>>>(bbox, priors, masked, labels, out);
}

// Round 3
// 264.352 us; speedup vs baseline: 1.1055x; 1.0088x over previous
//
#include <hip/hip_runtime.h>
#include <cstddef>
#include <cstdint>

// Problem constants (match reference)
#define BB 16
#define NN 33600
#define CC 80
#define MAXN 100
#define NBINS 4096
#define MAXC 1024
#define SCORE_THR_F 0.05f
#define IOU_THR_F 0.65f

#define NCHUNK 525            // NN / 64
#define K1_CPB 5              // chunks per block; 525 = 5*105 -> static trip count
#define K1_GX (NCHUNK / K1_CPB)  // 105
#define K2T 1024              // k2 threads (16 waves)
#define BPT (NBINS / K2T)     // 4 bins per thread in the scan
#define K2IT 9                // ceil((NN/4) / K2T) = ceil(8400/1024)

typedef float f4 __attribute__((ext_vector_type(4)));

// K1: 4 threads per row, 5 row-chunks per block (static trip count -> full
// unroll, up to 25 independent f4 loads in flight per wave). Computes
// masked = sigmoid(max_c cls)*sigmoid(obj) (-inf if < thr) AND label = argmax_c cls
// (sigmoid is monotone so argmax over raw logits == reference's argmax over sigmoid).
__global__ __launch_bounds__(256) void k1_score(const float* __restrict__ cls,
                                                const float* __restrict__ obj,
                                                float* __restrict__ masked,
                                                unsigned char* __restrict__ labels) {
  const int b = blockIdx.y;
  const int q = threadIdx.x & 3;
  const int r = threadIdx.x >> 2;
  const int c0 = blockIdx.x * K1_CPB;
#pragma unroll
  for (int cc = 0; cc < K1_CPB; cc++) {
    const int n = (c0 + cc) * 64 + r;
    const f4* row = (const f4*)(cls + ((size_t)b * NN + n) * CC);
    float m = -INFINITY;
    int lab = 0;
#pragma unroll
    for (int j = 0; j < 5; j++) {
      f4 v = __builtin_nontemporal_load(row + q + 4 * j);  // cls is stream-once
      const int cb = (q + 4 * j) * 4;
      if (v.x > m) { m = v.x; lab = cb; }      // strict >: first occurrence on ties
      if (v.y > m) { m = v.y; lab = cb + 1; }
      if (v.z > m) { m = v.z; lab = cb + 2; }
      if (v.w > m) { m = v.w; lab = cb + 3; }
    }
#pragma unroll
    for (int d = 1; d < 4; d <<= 1) {
      float m2 = __shfl_xor(m, d, 4);
      int l2 = __shfl_xor(lab, d, 4);
      if (m2 > m || (m2 == m && l2 < lab)) { m = m2; lab = l2; }  // smaller idx on tie
    }
    if (q == 0) {
      const size_t bn = (size_t)b * NN + n;
      float o = obj[bn];
      float s = (1.0f / (1.0f + expf(-m))) * (1.0f / (1.0f + expf(-o)));
      masked[bn] = (s >= SCORE_THR_F) ? s : -INFINITY;
      labels[bn] = (unsigned char)lab;
    }
  }
}

__device__ __forceinline__ int score_bin(float s) {
  return min(NBINS - 1, (int)(s * (float)NBINS));
}

// K2: one block (1024 threads) per batch. Loads issued early into registers
// (latency hidden under LDS init) -> histogram -> wave-shfl suffix scan ->
// compact (from registers, no global re-read) -> rank-select top-100 ->
// decode (labels precomputed by k1) -> pairwise suppression bitmask ->
// wave-0 register greedy scan -> write.
__global__ __launch_bounds__(K2T) void k2_all(const float* __restrict__ bbox,
                                              const float* __restrict__ priors,
                                              const float* __restrict__ masked,
                                              const unsigned char* __restrict__ labels,
                                              float* __restrict__ out) {
  const int b = blockIdx.x;
  const int tid = threadIdx.x;
  const int lane = tid & 63;
  const int wv = tid >> 6;  // wave index, 0..15

  __shared__ int hist[NBINS];
  __shared__ int wtot[K2T / 64];
  __shared__ int s_t, s_cnt;
  __shared__ float cs[MAXC];
  __shared__ int ci[MAXC];
  __shared__ int sel[MAXN];               // original anchor index, -1 if empty
  __shared__ float sb[MAXN][4];           // x1,y1,x2,y2
  __shared__ float ssc[MAXN];
  __shared__ int slab[MAXN];
  __shared__ unsigned int sup[MAXN][4];   // suppression bitmask (j bits), j>i only
  __shared__ unsigned long long keep_lo, keep_hi;

  const f4* msc4 = (const f4*)(masked + (size_t)b * NN);

  // Issue all global loads FIRST (independent of LDS) — L3 latency hides
  // under the init phase below. <=9 f4 per thread = 36 VGPRs, static indices.
  f4 vals[K2IT];
#pragma unroll
  for (int it = 0; it < K2IT; it++) {
    const int i = tid + it * K2T;
    if (i < NN / 4) vals[it] = msc4[i];
  }

  // Merged init phase (one barrier): hist, sup, sel, scalars
  for (int i = tid; i < NBINS; i += K2T) hist[i] = 0;
  for (int i = tid; i < MAXN * 4; i += K2T) ((unsigned int*)sup)[i] = 0;
  if (tid < MAXN) sel[tid] = -1;
  if (tid == 0) { s_t = 0; s_cnt = 0; }
  __syncthreads();

  // Pass 1: LDS histogram of valid scores (from registers)
#pragma unroll
  for (int it = 0; it < K2IT; it++) {
    const int i = tid + it * K2T;
    if (i < NN / 4) {
      f4 v = vals[it];
      if (v.x >= SCORE_THR_F) atomicAdd(&hist[score_bin(v.x)], 1);
      if (v.y >= SCORE_THR_F) atomicAdd(&hist[score_bin(v.y)], 1);
      if (v.z >= SCORE_THR_F) atomicAdd(&hist[score_bin(v.z)], 1);
      if (v.w >= SCORE_THR_F) atomicAdd(&hist[score_bin(v.w)], 1);
    }
  }
  __syncthreads();

  // Suffix scan via wave shuffles: thread t owns bins [t*BPT, t*BPT+BPT).
  // S = suffix count starting at this thread's first bin.
  int gsum = 0;
#pragma unroll
  for (int j = 0; j < BPT; j++) gsum += hist[tid * BPT + j];
  int sfx = gsum;
#pragma unroll
  for (int off = 1; off < 64; off <<= 1) {
    int t2 = __shfl_down(sfx, off);
    if (lane + off < 64) sfx += t2;
  }
  if (lane == 0) wtot[wv] = sfx;
  __syncthreads();
  int offw = 0;
#pragma unroll
  for (int w = 0; w < K2T / 64; w++) offw += (w > wv) ? wtot[w] : 0;
  const int S = sfx + offw;
  // Unique boundary owner: 100 in (S - gsum, S] and gsum > 0
  if (S >= MAXN && S - gsum < MAXN) {
    int running = S - gsum;
    for (int bin = tid * BPT + BPT - 1; bin >= tid * BPT; bin--) {
      running += hist[bin];
      if (running >= MAXN) { s_t = bin; break; }
    }
  }
  __syncthreads();
  const int t = s_t;

  // Pass 2: compact candidates with bin >= t into LDS (from registers)
#pragma unroll
  for (int it = 0; it < K2IT; it++) {
    const int i = tid + it * K2T;
    if (i < NN / 4) {
      f4 v = vals[it];
      const int base = i * 4;
      if (v.x >= SCORE_THR_F && score_bin(v.x) >= t) {
        int p = atomicAdd(&s_cnt, 1); if (p < MAXC) { cs[p] = v.x; ci[p] = base; }
      }
      if (v.y >= SCORE_THR_F && score_bin(v.y) >= t) {
        int p = atomicAdd(&s_cnt, 1); if (p < MAXC) { cs[p] = v.y; ci[p] = base + 1; }
      }
      if (v.z >= SCORE_THR_F && score_bin(v.z) >= t) {
        int p = atomicAdd(&s_cnt, 1); if (p < MAXC) { cs[p] = v.z; ci[p] = base + 2; }
      }
      if (v.w >= SCORE_THR_F && score_bin(v.w) >= t) {
        int p = atomicAdd(&s_cnt, 1); if (p < MAXC) { cs[p] = v.w; ci[p] = base + 3; }
      }
    }
  }
  __syncthreads();
  const int C = min(s_cnt, MAXC);

  // Rank by counting: rank = #{j : (s_j,i_j) before (s_i,i_i)}; ranks unique
  // (descending score, ascending index on ties — stable argsort semantics).
  for (int i = tid; i < C; i += K2T) {
    float si = cs[i]; int ii = ci[i];
    int r = 0;
    for (int j = 0; j < C; j++) {
      float sj = cs[j]; int ij = ci[j];
      r += (sj > si) || (sj == si && ij < ii);
    }
    if (r < MAXN) { sel[r] = ii; ssc[r] = si; }
  }
  __syncthreads();

  // Decode for the <=100 winners; label comes precomputed from k1
  if (tid < MAXN) {
    int idx = sel[tid];
    if (idx >= 0) {
      f4 p = ((const f4*)priors)[idx];                 // [x*s, y*s, s, s]
      f4 d = ((const f4*)bbox)[(size_t)b * NN + idx];  // [dx, dy, dw, dh]
      float cx = d.x * p.z + p.x;
      float cy = d.y * p.w + p.y;
      float hw = expf(d.z) * p.z * 0.5f;
      float hh = expf(d.w) * p.w * 0.5f;
      sb[tid][0] = cx - hw; sb[tid][1] = cy - hh;
      sb[tid][2] = cx + hw; sb[tid][3] = cy + hh;
      slab[tid] = labels[(size_t)b * NN + idx];
    } else {
      sb[tid][0] = 0.f; sb[tid][1] = 0.f; sb[tid][2] = 0.f; sb[tid][3] = 0.f;
      ssc[tid] = 0.f; slab[tid] = -1;
    }
  }
  __syncthreads();

  // Pairwise IOUs -> suppression bitmask (only j > i, same label, iou >= thr)
  for (int p = tid; p < MAXN * MAXN; p += K2T) {
    int i = p / MAXN, j = p % MAXN;
    if (j > i && sel[i] >= 0 && sel[j] >= 0 && slab[i] == slab[j]) {
      float xx1 = fmaxf(sb[i][0], sb[j][0]);
      float yy1 = fmaxf(sb[i][1], sb[j][1]);
      float xx2 = fminf(sb[i][2], sb[j][2]);
      float yy2 = fminf(sb[i][3], sb[j][3]);
      float inter = fmaxf(xx2 - xx1, 0.f) * fmaxf(yy2 - yy1, 0.f);
      float ai = (sb[i][2] - sb[i][0]) * (sb[i][3] - sb[i][1]);
      float aj = (sb[j][2] - sb[j][0]) * (sb[j][3] - sb[j][1]);
      float iou = inter / (ai + aj - inter + 1e-8f);
      if (iou >= IOU_THR_F) atomicOr(&sup[i][j >> 5], 1u << (j & 31));
    }
  }
  __syncthreads();

  // Greedy scan in wave 0: suppression rows live in lane registers, broadcast
  // via shfl (~5 cyc) instead of serial LDS round-trips (~120 cyc each).
  if (tid < 64) {
    unsigned a0 = sup[lane][0], a1 = sup[lane][1], a2 = sup[lane][2], a3 = sup[lane][3];
    unsigned b0 = 0, b1 = 0, b2 = 0, b3 = 0;
    if (lane + 64 < MAXN) {
      b0 = sup[lane + 64][0]; b1 = sup[lane + 64][1];
      b2 = sup[lane + 64][2]; b3 = sup[lane + 64][3];
    }
    unsigned long long lo = __ballot(sel[lane] >= 0);                          // rows 0..63
    unsigned long long hi = __ballot(lane + 64 < MAXN && sel[lane + 64] >= 0); // rows 64..99
    for (int i = 0; i < MAXN; i++) {
      bool kb = (i < 64) ? ((lo >> i) & 1ull) : ((hi >> (i - 64)) & 1ull);
      if (kb) {  // uniform across the wave: lo/hi identical in all lanes
        unsigned s0, s1, s2, s3;
        if (i < 64) {
          s0 = (unsigned)__shfl((int)a0, i); s1 = (unsigned)__shfl((int)a1, i);
          s2 = (unsigned)__shfl((int)a2, i); s3 = (unsigned)__shfl((int)a3, i);
        } else {
          s0 = (unsigned)__shfl((int)b0, i - 64); s1 = (unsigned)__shfl((int)b1, i - 64);
          s2 = (unsigned)__shfl((int)b2, i - 64); s3 = (unsigned)__shfl((int)b3, i - 64);
        }
        lo &= ~(((unsigned long long)s1 << 32) | s0);
        hi &= ~(((unsigned long long)s3 << 32) | s2);
      }
    }
    if (lane == 0) { keep_lo = lo; keep_hi = hi; }
  }
  __syncthreads();

  // Write output: dets [B,100,6] then keep [B,100] as 0.0/1.0
  if (tid < MAXN) {
    int k = tid;
    unsigned long long kw = (k < 64) ? keep_lo : keep_hi;
    int kbit = (k < 64) ? k : k - 64;
    bool kp = (kw >> kbit) & 1ull;
    float* row = out + ((size_t)b * MAXN + k) * 6;
    if (kp) {
      row[0] = sb[k][0]; row[1] = sb[k][1]; row[2] = sb[k][2]; row[3] = sb[k][3];
      row[4] = ssc[k];   row[5] = (float)slab[k];
    } else {
      row[0] = 0.f; row[1] = 0.f; row[2] = 0.f; row[3] = 0.f;
      row[4] = 0.f; row[5] = -1.f;
    }
    out[(size_t)BB * MAXN * 6 + (size_t)b * MAXN + k] = kp ? 1.0f : 0.0f;
  }
}

extern "C" void kernel_launch(void* const* d_in, const int* in_sizes, int n_in,
                              void* d_out, int out_size, void* d_ws, size_t ws_size,
                              hipStream_t stream) {
  const float* cls    = (const float*)d_in[0];  // [B,N,C]
  const float* bbox   = (const float*)d_in[1];  // [B,N,4]
  const float* obj    = (const float*)d_in[2];  // [B,N]
  const float* priors = (const float*)d_in[3];  // [N,4]
  float* out = (float*)d_out;                   // [B,100,6] ++ [B,100]
  float* masked = (float*)d_ws;                 // [B,N] masked scores (2.15 MB)
  unsigned char* labels = (unsigned char*)(masked + (size_t)BB * NN);  // [B,N] u8

  k1_score<<<dim3(K1_GX, BB), 256, 0, stream>>>(cls, obj, masked, labels);
  k2_all<<<BB, K2T, 0, stream>>>(bbox, priors, masked, labels, out);
}